// Round 8
// baseline (17634.230 us; speedup 1.0000x reference)
//
#include <hip/hip_runtime.h>

// ============================================================================
// 2-layer LSTM, persistent kernel, MI355X — round 8.
// R7 (8.45 ms, correct) was stall-bound: 19 __syncthreads/phase + per-chunk
// vmcnt(0) drains (LLC ~600cy > CHUNK ~320cy) from COOPERATIVE staging, plus a
// 3-hop sleep(4) grid barrier. But the kway k-split means each wave consumes a
// DISJOINT k-slice -> staging made wave-private (own 8KB LDS region per wave):
//   * per-chunk barriers 19 -> 0 (same-wave ds_write->ds_read, compiler waits)
//   * 2 waves/SIMD free-run -> each hides the other's memory stalls
//   * flat 2-hop grid barrier: 8 group counters, wave0 polls all 8 in
//     parallel (lane<8 + shfl reduce), s_sleep(1)
// Everything else verbatim from R7 (correct 5x, absmax 4.9e-3): packed
// weights + formulas, LDW/CHUNK shapes, reduce2/ew, sc01 stores, nt loads.
// ============================================================================

typedef unsigned int u32;
typedef unsigned short u16;
typedef __attribute__((ext_vector_type(8))) short bf16x8;
typedef __attribute__((ext_vector_type(4))) float f32x4;

#define MFMA __builtin_amdgcn_mfma_f32_16x16x32_bf16
#define HB (256 * 1024)   // h buffer elems per parity

__device__ __forceinline__ u16 f2bf(float f) {
  u32 u = __float_as_uint(f);
  u += 0x7fffu + ((u >> 16) & 1u);   // RNE (inputs finite)
  return (u16)(u >> 16);
}
__device__ __forceinline__ float sigm(float v) { return 1.f / (1.f + __expf(-v)); }
__device__ __forceinline__ float tanh_(float v) { return 1.f - 2.f / (__expf(2.f * v) + 1.f); }

__device__ __forceinline__ u32 ld_u32_sc01(const u32* p) {
  u32 v;
  asm volatile("global_load_dword %0, %1, off sc0 sc1\n\ts_waitcnt vmcnt(0)"
               : "=v"(v) : "v"(p) : "memory");
  return v;
}
__device__ __forceinline__ void st_u32_sc01(u32* p, u32 v) {
  asm volatile("global_store_dword %0, %1, off sc0 sc1" :: "v"(p), "v"(v) : "memory");
}
__device__ __forceinline__ void st_f32_sc01(float* p, float v) {
  asm volatile("global_store_dword %0, %1, off sc0 sc1" :: "v"(p), "v"(v) : "memory");
}

// ---------------- prologue: f32 -> bf16 packed-fragment weights ----------------
// (verbatim from R7)
__global__ void __launch_bounds__(256) wconv(
    const float* __restrict__ Wx0, const float* __restrict__ Wh0,
    const float* __restrict__ Wx1, const float* __restrict__ Wh1,
    u16* __restrict__ W1p, u16* __restrict__ W0p, u16* __restrict__ X0p) {
  const u32 NG1 = 1048576u, NG0 = 524288u, NGX = 32768u;
  u32 g = blockIdx.x * 256u + threadIdx.x;
  const float* src; u16* dst;
  if (g < NG1) {
    u32 lane = g & 63u, f = (g >> 6) & 1u, jj = (g >> 7) & 1u, c = (g >> 8) & 7u;
    u32 kway = (g >> 11) & 3u, s = (g >> 13) & 1u, u0idx = g >> 14;
    u32 i15 = lane & 15u, kq = lane >> 4;
    u32 row = (2u * f + (i15 >> 3)) * 1024u + u0idx * 16u + s * 8u + (i15 & 7u);
    u32 k = (kway + 4u * (2u * c + jj)) * 32u + kq * 8u;
    src = (k < 1024u) ? Wx1 + (size_t)row * 1024 + k
                      : Wh1 + (size_t)row * 1024 + (k - 1024u);
    dst = W1p + (size_t)g * 8;
  } else if (g < NG1 + NG0) {
    u32 h = g - NG1;
    u32 lane = h & 63u, f = (h >> 6) & 1u, jj = (h >> 7) & 1u, c = (h >> 8) & 3u;
    u32 kway = (h >> 10) & 3u, s = (h >> 12) & 1u, u0idx = h >> 13;
    u32 i15 = lane & 15u, kq = lane >> 4;
    u32 row = (2u * f + (i15 >> 3)) * 1024u + u0idx * 16u + s * 8u + (i15 & 7u);
    u32 k = (kway + 4u * (2u * c + jj)) * 32u + kq * 8u;
    src = Wh0 + (size_t)row * 1024 + k;
    dst = W0p + (size_t)h * 8;
  } else if (g < NG1 + NG0 + NGX) {
    u32 h = g - NG1 - NG0;
    u32 lane = h & 63u, f = (h >> 6) & 1u, kway = (h >> 7) & 1u;
    u32 s = (h >> 8) & 1u, u0idx = h >> 9;
    u32 i15 = lane & 15u, kq = lane >> 4;
    u32 row = (2u * f + (i15 >> 3)) * 1024u + u0idx * 16u + s * 8u + (i15 & 7u);
    u32 k = kway * 32u + kq * 8u;
    src = Wx0 + (size_t)row * 64 + k;
    dst = X0p + (size_t)h * 8;
  } else return;
  float4 v0 = *(const float4*)src, v1 = *(const float4*)(src + 4);
  bf16x8 r;
  r[0] = (short)f2bf(v0.x); r[1] = (short)f2bf(v0.y);
  r[2] = (short)f2bf(v0.z); r[3] = (short)f2bf(v0.w);
  r[4] = (short)f2bf(v1.x); r[5] = (short)f2bf(v1.y);
  r[6] = (short)f2bf(v1.z); r[7] = (short)f2bf(v1.w);
  *(bf16x8*)dst = r;
}

// ---- per-chunk weight load (single set, per-call opaque offsets) ----
#define LDW(c) do {                                                            \
  u32 o0_ = bW0 + (u32)((c) * 2048), o1_ = bW1 + (u32)((c) * 2048);            \
  asm volatile("" : "+v"(o0_), "+v"(o1_));                                     \
  _Pragma("unroll")                                                            \
  for (int jj_ = 0; jj_ < 2; ++jj_)                                            \
    _Pragma("unroll")                                                          \
    for (int f_ = 0; f_ < 2; ++f_) {                                           \
      W[jj_][0][f_] = *(const bf16x8*)(WP + o0_ + (u32)(jj_*1024 + f_*512));   \
      W[jj_][1][f_] = *(const bf16x8*)(WP + o1_ + (u32)(jj_*1024 + f_*512));   \
    }                                                                          \
} while (0)

// ---- per-chunk MFMA: 2 jj x 4 mf x 4 (s,f) = 32 MFMA, wave-private A ----
#define CHUNK() do {                                                           \
  _Pragma("unroll")                                                            \
  for (int jj_ = 0; jj_ < 2; ++jj_) {                                          \
    _Pragma("unroll")                                                          \
    for (int mf_ = 0; mf_ < 4; ++mf_) {                                        \
      bf16x8 a_ = readA(mf_, jj_);                                             \
      _Pragma("unroll")                                                        \
      for (int s_ = 0; s_ < 2; ++s_)                                           \
        _Pragma("unroll")                                                      \
        for (int f_ = 0; f_ < 2; ++f_)                                         \
          acc[mf_][s_][f_] = MFMA(a_, W[jj_][s_][f_], acc[mf_][s_][f_], 0,0,0);\
    }                                                                          \
  }                                                                            \
} while (0)

__global__ void __launch_bounds__(256, 2)
lstm_persist(const float* __restrict__ x,
             const float* __restrict__ b0, const float* __restrict__ b1,
             const float* __restrict__ fcW, const float* __restrict__ fcb,
             const u16* __restrict__ W1p, const u16* __restrict__ W0p,
             const u16* __restrict__ X0p,
             u16* __restrict__ h0b, u16* __restrict__ h1b,
             float* __restrict__ h1f, u32* __restrict__ bar,
             float* __restrict__ out)
{
  const int tid = threadIdx.x, blk = blockIdx.x;
  const int lane = tid & 63, w = tid >> 6;
  const int kway = w;                 // wave = k-split lane (0..3)
  const int L = blk >> 8;             // 0: layer0 WG, 1: layer1 WG
  const int sub = blk & 255;
  const int m0 = (sub >> 6) << 6;     // batch tile base
  const int u0idx = sub & 63;
  const int u0 = u0idx << 4;          // hidden-unit base

  __shared__ short Awv[4][4096];      // per-WAVE 8KB k-slice regions
  __shared__ float gA[64][68];        // k-reduce region A
  __shared__ float gB[64][68];        // k-reduce region B
  __shared__ float cbuf[64][16];      // persistent c state (own layer)

  for (int i = tid; i < 64 * 16; i += 256) ((float*)cbuf)[i] = 0.f;

  const int i15 = lane & 15, kq = lane >> 4;

  // packed-weight base offsets (u32 elem offsets)
  const u32 key0 = (u32)((u0idx << 1) | 0), key1 = (u32)((u0idx << 1) | 1);
  const u32 bW0 = ((key0 << 2) | (u32)kway) * (L ? 16384u : 8192u) + (u32)lane * 8u;
  const u32 bW1 = ((key1 << 2) | (u32)kway) * (L ? 16384u : 8192u) + (u32)lane * 8u;
  const u32 bX0 = ((key0 << 1) | (u32)kway) * 1024u + (u32)lane * 8u;  // kway<2
  const u32 bX1 = ((key1 << 1) | (u32)kway) * 1024u + (u32)lane * 8u;
  const u16* WP = L ? W1p : W0p;

  float bias[2][2];
#pragma unroll
  for (int s_ = 0; s_ < 2; ++s_)
#pragma unroll
    for (int f_ = 0; f_ < 2; ++f_) {
      int rowf = ((f_ << 1) + (i15 >> 3)) * 1024 + u0 + s_ * 8 + (i15 & 7);
      bias[s_][f_] = (kway == 0) ? (L ? b1[rowf] : b0[rowf]) : 0.f;
    }

  // wave-private staging maps: 512 slots of 16B per chunk, 8 per lane
  int goff[8], lds16[8];
#pragma unroll
  for (int cc = 0; cc < 8; ++cc) {
    int sid = cc * 64 + lane;
    int row = sid >> 3, jj = (sid >> 2) & 1, kq4 = sid & 3;
    goff[cc]  = ((m0 + row) << 10) + jj * 128 + kq4 * 8;
    lds16[cc] = row * 64 + (((((jj << 2) | kq4) ^ (row & 7))) << 3);
  }

  bf16x8 v[8];
  auto ld_h = [&](const u16* src, int cm) {
    const int colb = (kway << 5) + (cm << 8);   // kway*32 + cm*256
#pragma unroll
    for (int cc = 0; cc < 8; ++cc)
      v[cc] = __builtin_nontemporal_load((const bf16x8*)(src + goff[cc] + colb));
  };
  auto dsw = [&]() {
#pragma unroll
    for (int cc = 0; cc < 8; ++cc)
      *(bf16x8*)&Awv[kway][lds16[cc]] = v[cc];
  };

  auto readA = [&](int mf, int jj) -> bf16x8 {
    int row = (mf << 4) | i15;
    int sl = ((jj << 2) | kq) ^ (row & 7);
    return *(const bf16x8*)&Awv[kway][row * 64 + (sl << 3)];
  };

  bf16x8 W[2][2][2];      // [jj][s][f] single-set JIT weights (32 regs)
  f32x4 acc[4][2][2];     // [mf][s][f] (64 regs)

  auto acc_init = [&]() {
#pragma unroll
    for (int mf = 0; mf < 4; ++mf)
#pragma unroll
      for (int s_ = 0; s_ < 2; ++s_)
#pragma unroll
        for (int f_ = 0; f_ < 2; ++f_) {
          float bv = bias[s_][f_];
          acc[mf][s_][f_][0] = bv; acc[mf][s_][f_][1] = bv;
          acc[mf][s_][f_][2] = bv; acc[mf][s_][f_][3] = bv;
        }
  };

  auto reduce2 = [&]() {   // 4 kway partials -> gA + gB (verbatim R7)
    if (kway < 2) {
      float (*g)[68] = kway ? gB : gA;
#pragma unroll
      for (int mf = 0; mf < 4; ++mf)
#pragma unroll
        for (int s_ = 0; s_ < 2; ++s_)
#pragma unroll
          for (int f_ = 0; f_ < 2; ++f_)
#pragma unroll
            for (int r = 0; r < 4; ++r)
              g[(mf << 4) + (kq << 2) + r][(s_ << 5) + (f_ << 4) + i15] = acc[mf][s_][f_][r];
    }
    __syncthreads();
    if (kway >= 2) {
      float (*g)[68] = (kway == 3) ? gB : gA;
#pragma unroll
      for (int mf = 0; mf < 4; ++mf)
#pragma unroll
        for (int s_ = 0; s_ < 2; ++s_)
#pragma unroll
          for (int f_ = 0; f_ < 2; ++f_)
#pragma unroll
            for (int r = 0; r < 4; ++r)
              g[(mf << 4) + (kq << 2) + r][(s_ << 5) + (f_ << 4) + i15] += acc[mf][s_][f_][r];
    }
    __syncthreads();
  };

  auto ew = [&](u16* hdst, bool wf32) {   // verbatim R7
    int row = tid >> 2, un = (tid & 3) << 2;
    float hq[4];
#pragma unroll
    for (int q = 0; q < 4; ++q) {
      int u = un + q;
      int cb = ((u >> 3) << 5) | (u & 7);
      float gi = gA[row][cb]      + gB[row][cb];
      float gf = gA[row][cb + 8]  + gB[row][cb + 8];
      float gg = gA[row][cb + 16] + gB[row][cb + 16];
      float go = gA[row][cb + 24] + gB[row][cb + 24];
      float ii = sigm(gi), ff = sigm(gf), g2 = tanh_(gg), oo = sigm(go);
      float c = ff * cbuf[row][u] + ii * g2;
      cbuf[row][u] = c;
      hq[q] = oo * tanh_(c);
    }
    size_t idx = ((size_t)(m0 + row) << 10) + u0 + un;
    st_u32_sc01((u32*)(hdst + idx),     (u32)f2bf(hq[0]) | ((u32)f2bf(hq[1]) << 16));
    st_u32_sc01((u32*)(hdst + idx + 2), (u32)f2bf(hq[2]) | ((u32)f2bf(hq[3]) << 16));
    if (wf32) {
      st_f32_sc01(h1f + idx,     hq[0]); st_f32_sc01(h1f + idx + 1, hq[1]);
      st_f32_sc01(h1f + idx + 2, hq[2]); st_f32_sc01(h1f + idx + 3, hq[3]);
    }
  };

  // flat 2-hop grid barrier: 8 group counters, wave0 polls all 8 in parallel
  auto gridbar = [&](int t) {
    __syncthreads();                  // per-wave vmcnt drain -> h stores at LLC
    if (w == 0) {
      const u32 p1 = (u32)(t + 1);
      if (lane == 0)
        __hip_atomic_fetch_add(bar + (blk & 7) * 32, 1u,
                               __ATOMIC_RELAXED, __HIP_MEMORY_SCOPE_AGENT);
      const u32 target = 512u * p1;
      for (;;) {
        u32 vv = 0;
        if (lane < 8) vv = ld_u32_sc01(bar + lane * 32);
        vv += __shfl_xor(vv, 1); vv += __shfl_xor(vv, 2); vv += __shfl_xor(vv, 4);
        if (__shfl(vv, 0) >= target) break;
        __builtin_amdgcn_s_sleep(1);
      }
    }
    __syncthreads();
  };

  // x staging maps (kway<2 only): 256 slots, 4 per lane
  int gxoff[4], ldsx[4];
#pragma unroll
  for (int cc = 0; cc < 4; ++cc) {
    int sid = cc * 64 + lane;
    int row = sid >> 2, kq4 = sid & 3;
    gxoff[cc] = (m0 + row) * 32768 + kway * 32 + kq4 * 8;
    ldsx[cc]  = row * 64 + ((kq4 ^ (row & 7)) << 3);
  }

  // ---------------- phase loop: phase t = { L0(t), L1(t-1) } ----------------
#pragma unroll 1
  for (int t = 0; t <= 512; ++t) {
    if (L == 0) {
      if (t < 512) {
        const u16* h0rd = h0b + ((t + 1) & 1) * HB;
        u16* h0wr = h0b + (t & 1) * HB;
        acc_init();
        ld_h(h0rd, 0);                       // h chunk0 loads in flight
        if (kway < 2) {                      // wave-private x stage + x-tick
#pragma unroll
          for (int cc = 0; cc < 4; ++cc) {
            const float* g = x + gxoff[cc] + t * 64;
            float4 a0 = *(const float4*)g, a1 = *(const float4*)(g + 4);
            bf16x8 r;
            r[0] = (short)f2bf(a0.x); r[1] = (short)f2bf(a0.y);
            r[2] = (short)f2bf(a0.z); r[3] = (short)f2bf(a0.w);
            r[4] = (short)f2bf(a1.x); r[5] = (short)f2bf(a1.y);
            r[6] = (short)f2bf(a1.z); r[7] = (short)f2bf(a1.w);
            *(bf16x8*)&Awv[kway][ldsx[cc]] = r;
          }
          u32 ox0 = bX0, ox1 = bX1;
          asm volatile("" : "+v"(ox0), "+v"(ox1));
          bf16x8 X00 = *(const bf16x8*)(X0p + ox0);
          bf16x8 X01 = *(const bf16x8*)(X0p + ox0 + 512u);
          bf16x8 X10 = *(const bf16x8*)(X0p + ox1);
          bf16x8 X11 = *(const bf16x8*)(X0p + ox1 + 512u);
#pragma unroll
          for (int mf = 0; mf < 4; ++mf) {
            int row = (mf << 4) | i15;
            bf16x8 a = *(const bf16x8*)&Awv[kway][row * 64 + ((kq ^ (row & 7)) << 3)];
            acc[mf][0][0] = MFMA(a, X00, acc[mf][0][0], 0, 0, 0);
            acc[mf][0][1] = MFMA(a, X01, acc[mf][0][1], 0, 0, 0);
            acc[mf][1][0] = MFMA(a, X10, acc[mf][1][0], 0, 0, 0);
            acc[mf][1][1] = MFMA(a, X11, acc[mf][1][1], 0, 0, 0);
          }
        }
        dsw();                               // commit h chunk0 (overwrites x)
        ld_h(h0rd, 1); LDW(0); CHUNK(); dsw();
        ld_h(h0rd, 2); LDW(1); CHUNK(); dsw();
        ld_h(h0rd, 3); LDW(2); CHUNK(); dsw();
        LDW(3); CHUNK();
        reduce2();
        ew(h0wr, false);
      }
      gridbar(t);
    } else {
      if (t >= 1) {
        const u16* h0rd = h0b + ((t + 1) & 1) * HB;   // h0(t-1)
        const u16* h1rd = h1b + (t & 1) * HB;         // h1(t-2)
        u16* h1wr = h1b + ((t + 1) & 1) * HB;         // h1(t-1)
        acc_init();
        ld_h(h0rd, 0); dsw();
        ld_h(h0rd, 1); LDW(0); CHUNK(); dsw();
        ld_h(h0rd, 2); LDW(1); CHUNK(); dsw();
        ld_h(h0rd, 3); LDW(2); CHUNK(); dsw();
        ld_h(h1rd, 0); LDW(3); CHUNK(); dsw();
        ld_h(h1rd, 1); LDW(4); CHUNK(); dsw();
        ld_h(h1rd, 2); LDW(5); CHUNK(); dsw();
        ld_h(h1rd, 3); LDW(6); CHUNK(); dsw();
        LDW(7); CHUNK();
        reduce2();
        ew(h1wr, t == 512);
      }
      gridbar(t);
    }
  }

  // ---------------- fc epilogue (verbatim R7) ----------------
  if (blk < 64) {
    const int row = (blk << 2) | w;
    const float* hrow = h1f + ((size_t)row << 10);
#pragma unroll 1
    for (int o = 0; o < 12; ++o) {
      const float* wrow = fcW + o * 1024;
      float p = 0.f;
#pragma unroll
      for (int j = 0; j < 16; ++j) {
        int k = (j << 6) | lane;
        p += __builtin_nontemporal_load(hrow + k) * wrow[k];
      }
#pragma unroll
      for (int off = 32; off > 0; off >>= 1) p += __shfl_down(p, off, 64);
      if (lane == 0) out[row * 12 + o] = p + fcb[o];
    }
  }
}

extern "C" void kernel_launch(void* const* d_in, const int* in_sizes, int n_in,
                              void* d_out, int out_size, void* d_ws, size_t ws_size,
                              hipStream_t stream) {
  (void)in_sizes; (void)n_in; (void)out_size; (void)ws_size;
  const float* x   = (const float*)d_in[0];
  const float* Wx0 = (const float*)d_in[1];
  const float* Wh0 = (const float*)d_in[2];
  const float* b0  = (const float*)d_in[3];
  const float* Wx1 = (const float*)d_in[4];
  const float* Wh1 = (const float*)d_in[5];
  const float* b1  = (const float*)d_in[6];
  const float* fcW = (const float*)d_in[7];
  const float* fcb = (const float*)d_in[8];

  char* ws = (char*)d_ws;
  u16* W1p   = (u16*)ws;                          // 16 MiB packed Wx1|Wh1
  u16* W0p   = (u16*)(ws + (16u << 20));          //  8 MiB packed Wh0
  u16* X0p   = (u16*)(ws + (24u << 20));          // 512 KiB packed Wx0
  u16* h0b   = (u16*)(ws + (25u << 20));          // 2 x 512 KiB
  u16* h1b   = (u16*)(ws + (26u << 20));          // 2 x 512 KiB
  float* h1f = (float*)(ws + (27u << 20));        // 1 MiB
  u32* bar   = (u32*)(ws + (28u << 20));          // counters

  hipMemsetAsync(ws + (25u << 20) + (1 << 19), 0, 1 << 19, stream);  // h0b[1]
  hipMemsetAsync(ws + (26u << 20) + (1 << 19), 0, 1 << 19, stream);  // h1b[1]
  hipMemsetAsync(bar, 0, 4096, stream);

  wconv<<<6272, 256, 0, stream>>>(Wx0, Wh0, Wx1, Wh1, W1p, W0p, X0p);
  lstm_persist<<<512, 256, 0, stream>>>(x, b0, b1, fcW, fcb,
                                        W1p, W0p, X0p,
                                        h0b, h1b, h1f, bar, (float*)d_out);
}

// Round 9
// 10633.624 us; speedup vs baseline: 1.6583x; 1.6583x over previous
//
#include <hip/hip_runtime.h>

// ============================================================================
// 2-layer LSTM, persistent kernel, MI355X — round 9.
// R8 lesson: single-set weights put MFMA behind a FIFO vmcnt that also waited
// for newer LLC h-loads -> serial chunk round trips (2x regression). Revert to
// R7 (8.45 ms, proven) and change ONE mechanism:
//   * Double-buffered Abuf -> stage_st targets the idle buffer: no
//     "readers-done" barrier, vmcnt drain overlaps CHUNK. 2 -> 1 barrier/chunk.
//   * LDS kept at 68KB (2 WGs/CU) by overlaying gA/gB on the Abuf union
//     (both Abuf buffers are dead during reduce2; pre-reduce barrier guards).
// Everything else VERBATIM from R7: cooperative staging, double-banked LDW
// (MFMA never waits vmcnt), x-tick, reduce2/ew math, sc01 h stores, nt h
// loads, leader-tree grid barrier (correct 6x, absmax 4.9e-3).
// ============================================================================

typedef unsigned int u32;
typedef unsigned short u16;
typedef __attribute__((ext_vector_type(8))) short bf16x8;
typedef __attribute__((ext_vector_type(4))) float f32x4;

#define MFMA __builtin_amdgcn_mfma_f32_16x16x32_bf16
#define HB (256 * 1024)   // h buffer elems per parity

__device__ __forceinline__ u16 f2bf(float f) {
  u32 u = __float_as_uint(f);
  u += 0x7fffu + ((u >> 16) & 1u);   // RNE (inputs finite)
  return (u16)(u >> 16);
}
__device__ __forceinline__ float sigm(float v) { return 1.f / (1.f + __expf(-v)); }
__device__ __forceinline__ float tanh_(float v) { return 1.f - 2.f / (__expf(2.f * v) + 1.f); }

__device__ __forceinline__ u32 ld_u32_sc01(const u32* p) {
  u32 v;
  asm volatile("global_load_dword %0, %1, off sc0 sc1\n\ts_waitcnt vmcnt(0)"
               : "=v"(v) : "v"(p) : "memory");
  return v;
}
__device__ __forceinline__ void st_u32_sc01(u32* p, u32 v) {
  asm volatile("global_store_dword %0, %1, off sc0 sc1" :: "v"(p), "v"(v) : "memory");
}
__device__ __forceinline__ void st_f32_sc01(float* p, float v) {
  asm volatile("global_store_dword %0, %1, off sc0 sc1" :: "v"(p), "v"(v) : "memory");
}

// ---------------- prologue: f32 -> bf16 packed-fragment weights ----------------
// (verbatim from R7)
__global__ void __launch_bounds__(256) wconv(
    const float* __restrict__ Wx0, const float* __restrict__ Wh0,
    const float* __restrict__ Wx1, const float* __restrict__ Wh1,
    u16* __restrict__ W1p, u16* __restrict__ W0p, u16* __restrict__ X0p) {
  const u32 NG1 = 1048576u, NG0 = 524288u, NGX = 32768u;
  u32 g = blockIdx.x * 256u + threadIdx.x;
  const float* src; u16* dst;
  if (g < NG1) {
    u32 lane = g & 63u, f = (g >> 6) & 1u, jj = (g >> 7) & 1u, c = (g >> 8) & 7u;
    u32 kway = (g >> 11) & 3u, s = (g >> 13) & 1u, u0idx = g >> 14;
    u32 i15 = lane & 15u, kq = lane >> 4;
    u32 row = (2u * f + (i15 >> 3)) * 1024u + u0idx * 16u + s * 8u + (i15 & 7u);
    u32 k = (kway + 4u * (2u * c + jj)) * 32u + kq * 8u;
    src = (k < 1024u) ? Wx1 + (size_t)row * 1024 + k
                      : Wh1 + (size_t)row * 1024 + (k - 1024u);
    dst = W1p + (size_t)g * 8;
  } else if (g < NG1 + NG0) {
    u32 h = g - NG1;
    u32 lane = h & 63u, f = (h >> 6) & 1u, jj = (h >> 7) & 1u, c = (h >> 8) & 3u;
    u32 kway = (h >> 10) & 3u, s = (h >> 12) & 1u, u0idx = h >> 13;
    u32 i15 = lane & 15u, kq = lane >> 4;
    u32 row = (2u * f + (i15 >> 3)) * 1024u + u0idx * 16u + s * 8u + (i15 & 7u);
    u32 k = (kway + 4u * (2u * c + jj)) * 32u + kq * 8u;
    src = Wh0 + (size_t)row * 1024 + k;
    dst = W0p + (size_t)h * 8;
  } else if (g < NG1 + NG0 + NGX) {
    u32 h = g - NG1 - NG0;
    u32 lane = h & 63u, f = (h >> 6) & 1u, kway = (h >> 7) & 1u;
    u32 s = (h >> 8) & 1u, u0idx = h >> 9;
    u32 i15 = lane & 15u, kq = lane >> 4;
    u32 row = (2u * f + (i15 >> 3)) * 1024u + u0idx * 16u + s * 8u + (i15 & 7u);
    u32 k = kway * 32u + kq * 8u;
    src = Wx0 + (size_t)row * 64 + k;
    dst = X0p + (size_t)h * 8;
  } else return;
  float4 v0 = *(const float4*)src, v1 = *(const float4*)(src + 4);
  bf16x8 r;
  r[0] = (short)f2bf(v0.x); r[1] = (short)f2bf(v0.y);
  r[2] = (short)f2bf(v0.z); r[3] = (short)f2bf(v0.w);
  r[4] = (short)f2bf(v1.x); r[5] = (short)f2bf(v1.y);
  r[6] = (short)f2bf(v1.z); r[7] = (short)f2bf(v1.w);
  *(bf16x8*)dst = r;
}

// ---- per-chunk weight load: DOUBLE-BANKED (prefetch next chunk's W) ----
#define LDW(bank, c) do {                                                      \
  u32 o0_ = bW[0] + (u32)((c) * 2048), o1_ = bW[1] + (u32)((c) * 2048);        \
  asm volatile("" : "+v"(o0_), "+v"(o1_));                                     \
  _Pragma("unroll")                                                            \
  for (int jj_ = 0; jj_ < 2; ++jj_)                                            \
    _Pragma("unroll")                                                          \
    for (int f_ = 0; f_ < 2; ++f_) {                                           \
      W[bank][jj_][0][f_] = *(const bf16x8*)(WP + o0_ + (u32)(jj_*1024+f_*512));\
      W[bank][jj_][1][f_] = *(const bf16x8*)(WP + o1_ + (u32)(jj_*1024+f_*512));\
    }                                                                          \
} while (0)

// ---- per-chunk MFMA: 2 jj x 4 mf x 4 (s,f) = 32 MFMA on buffer bsel ----
#define CHUNK(bsel, bank) do {                                                 \
  _Pragma("unroll")                                                            \
  for (int jj_ = 0; jj_ < 2; ++jj_) {                                          \
    const int kin_ = (kway + (jj_ << 2)) << 5;                                 \
    _Pragma("unroll")                                                          \
    for (int mf_ = 0; mf_ < 4; ++mf_) {                                        \
      bf16x8 a_ = readA(bsel, mf_, kin_);                                      \
      _Pragma("unroll")                                                        \
      for (int s_ = 0; s_ < 2; ++s_)                                           \
        _Pragma("unroll")                                                      \
        for (int f_ = 0; f_ < 2; ++f_)                                         \
          acc[mf_][s_][f_] = MFMA(a_, W[bank][jj_][s_][f_],                    \
                                  acc[mf_][s_][f_], 0, 0, 0);                  \
    }                                                                          \
  }                                                                            \
} while (0)

union SMemU {                        // Abuf (compute) / gA,gB (reduce) overlay
  short Ab[2][16384];                // 2 x 32KB staged A chunks
  float G[2][64][68];                // k-reduce regions (both Ab dead then)
};

__global__ void __launch_bounds__(256, 2)
lstm_persist(const float* __restrict__ x,
             const float* __restrict__ b0, const float* __restrict__ b1,
             const float* __restrict__ fcW, const float* __restrict__ fcb,
             const u16* __restrict__ W1p, const u16* __restrict__ W0p,
             const u16* __restrict__ X0p,
             u16* __restrict__ h0b, u16* __restrict__ h1b,
             float* __restrict__ h1f, u32* __restrict__ bar,
             float* __restrict__ out)
{
  const int tid = threadIdx.x, blk = blockIdx.x;
  const int lane = tid & 63, w = tid >> 6;
  const int kway = w;                 // wave = k-split lane (0..3)
  const int L = blk >> 8;             // 0: layer0 WG, 1: layer1 WG
  const int sub = blk & 255;
  const int m0 = (sub >> 6) << 6;     // batch tile base
  const int u0idx = sub & 63;
  const int u0 = u0idx << 4;          // hidden-unit base

  __shared__ SMemU sm;                // 64KB
  __shared__ float cbuf[64][16];      // persistent c state (own layer)

  for (int i = tid; i < 64 * 16; i += 256) ((float*)cbuf)[i] = 0.f;

  const int i15 = lane & 15, kq = lane >> 4;

  // packed-weight base offsets (u32 elem offsets)
  u32 bW[2], bX[2];
#pragma unroll
  for (int s_ = 0; s_ < 2; ++s_) {
    u32 key = (u32)((u0idx << 1) | s_);
    bW[s_] = ((key << 2) | (u32)kway) * (L ? 16384u : 8192u) + (u32)lane * 8u;
    bX[s_] = ((key << 1) | (u32)kway) * 1024u + (u32)lane * 8u;  // kway<2 only
  }
  const u16* WP = L ? W1p : W0p;

  float bias[2][2];
#pragma unroll
  for (int s_ = 0; s_ < 2; ++s_)
#pragma unroll
    for (int f_ = 0; f_ < 2; ++f_) {
      int rowf = ((f_ << 1) + (i15 >> 3)) * 1024 + u0 + s_ * 8 + (i15 & 7);
      bias[s_][f_] = (kway == 0) ? (L ? b1[rowf] : b0[rowf]) : 0.f;
    }

  // cooperative staging maps: 2048 bf16x8 slots (64 rows x 32), 8 per thread
  int grow[8], ldsoff[8];
#pragma unroll
  for (int cc = 0; cc < 8; ++cc) {
    int slot = cc * 256 + tid;
    int row = slot >> 5, c = slot & 31;
    grow[cc]   = ((m0 + row) << 10) + (c << 3);
    ldsoff[cc] = (row << 8) + ((c ^ (row & 7)) << 3);
  }

  bf16x8 v[8];
  auto stage_ld = [&](const u16* src, int kbase) {
#pragma unroll
    for (int cc = 0; cc < 8; ++cc)
      v[cc] = __builtin_nontemporal_load((const bf16x8*)(src + grow[cc] + kbase));
  };
  auto stage_st = [&](int bsel) {
#pragma unroll
    for (int cc = 0; cc < 8; ++cc)
      *(bf16x8*)&sm.Ab[bsel][ldsoff[cc]] = v[cc];
  };

  auto readA = [&](int bsel, int mf, int kin) -> bf16x8 {
    int row = (mf << 4) | i15;
    int c = ((kin >> 3) + kq) ^ (row & 7);
    return *(const bf16x8*)&sm.Ab[bsel][(row << 8) + (c << 3)];
  };

  bf16x8 W[2][2][2][2];   // [bank][jj][s][f] double-banked weights (64 regs)
  f32x4 acc[4][2][2];     // [mf][s][f] (64 regs)

  auto acc_init = [&]() {
#pragma unroll
    for (int mf = 0; mf < 4; ++mf)
#pragma unroll
      for (int s_ = 0; s_ < 2; ++s_)
#pragma unroll
        for (int f_ = 0; f_ < 2; ++f_) {
          float bv = bias[s_][f_];
          acc[mf][s_][f_][0] = bv; acc[mf][s_][f_][1] = bv;
          acc[mf][s_][f_][2] = bv; acc[mf][s_][f_][3] = bv;
        }
  };

  auto reduce2 = [&]() {   // 4 kway partials -> G[0] + G[1] (R7 formulas)
    if (kway < 2) {
      float (*g)[68] = sm.G[kway];
#pragma unroll
      for (int mf = 0; mf < 4; ++mf)
#pragma unroll
        for (int s_ = 0; s_ < 2; ++s_)
#pragma unroll
          for (int f_ = 0; f_ < 2; ++f_)
#pragma unroll
            for (int r = 0; r < 4; ++r)
              g[(mf << 4) + (kq << 2) + r][(s_ << 5) + (f_ << 4) + i15] = acc[mf][s_][f_][r];
    }
    __syncthreads();
    if (kway >= 2) {
      float (*g)[68] = sm.G[kway - 2];
#pragma unroll
      for (int mf = 0; mf < 4; ++mf)
#pragma unroll
        for (int s_ = 0; s_ < 2; ++s_)
#pragma unroll
          for (int f_ = 0; f_ < 2; ++f_)
#pragma unroll
            for (int r = 0; r < 4; ++r)
              g[(mf << 4) + (kq << 2) + r][(s_ << 5) + (f_ << 4) + i15] += acc[mf][s_][f_][r];
    }
    __syncthreads();
  };

  auto ew = [&](u16* hdst, bool wf32) {   // verbatim R7 (gA/gB -> sm.G)
    int row = tid >> 2, un = (tid & 3) << 2;
    float hq[4];
#pragma unroll
    for (int q = 0; q < 4; ++q) {
      int u = un + q;
      int cb = ((u >> 3) << 5) | (u & 7);
      float gi = sm.G[0][row][cb]      + sm.G[1][row][cb];
      float gf = sm.G[0][row][cb + 8]  + sm.G[1][row][cb + 8];
      float gg = sm.G[0][row][cb + 16] + sm.G[1][row][cb + 16];
      float go = sm.G[0][row][cb + 24] + sm.G[1][row][cb + 24];
      float ii = sigm(gi), ff = sigm(gf), g2 = tanh_(gg), oo = sigm(go);
      float c = ff * cbuf[row][u] + ii * g2;
      cbuf[row][u] = c;
      hq[q] = oo * tanh_(c);
    }
    size_t idx = ((size_t)(m0 + row) << 10) + u0 + un;
    st_u32_sc01((u32*)(hdst + idx),     (u32)f2bf(hq[0]) | ((u32)f2bf(hq[1]) << 16));
    st_u32_sc01((u32*)(hdst + idx + 2), (u32)f2bf(hq[2]) | ((u32)f2bf(hq[3]) << 16));
    if (wf32) {
      st_f32_sc01(h1f + idx,     hq[0]); st_f32_sc01(h1f + idx + 1, hq[1]);
      st_f32_sc01(h1f + idx + 2, hq[2]); st_f32_sc01(h1f + idx + 3, hq[3]);
    }
  };

  auto gridbar = [&](int t) {       // verbatim R7 leader-tree barrier
    __syncthreads();                // drains vmcnt -> sc01 h stores at LLC
    if (tid == 0) {
      const int g = blk & 7;
      u32* gc   = bar + g * 32;
      u32* root = bar + 256;
      u32* gen  = bar + 288 + g * 32;
      const u32 p1 = (u32)(t + 1);
      __hip_atomic_fetch_add(gc, 1u, __ATOMIC_RELAXED, __HIP_MEMORY_SCOPE_AGENT);
      if (blk < 8) {
        while (ld_u32_sc01(gc) < 64u * p1) __builtin_amdgcn_s_sleep(4);
        __hip_atomic_fetch_add(root, 1u, __ATOMIC_RELAXED, __HIP_MEMORY_SCOPE_AGENT);
        while (ld_u32_sc01(root) < 8u * p1) __builtin_amdgcn_s_sleep(2);
        st_u32_sc01(gen, p1);
      } else {
        while (ld_u32_sc01(gen) < p1) __builtin_amdgcn_s_sleep(4);
      }
    }
    __syncthreads();
  };

  // ---------------- phase loop: phase t = { L0(t), L1(t-1) } ----------------
#pragma unroll 1
  for (int t = 0; t <= 512; ++t) {
    if (L == 0) {
      if (t < 512) {
        const u16* h0rd = h0b + ((t + 1) & 1) * HB;
        u16* h0wr = h0b + (t & 1) * HB;
        acc_init();
        // cooperative x stage into buf0 (R7 stage_x)
        {
          int row = tid >> 2, c4 = tid & 3;
          const float* g = x + ((size_t)(m0 + row) * 512 + t) * 64 + (c4 << 4);
          float4 a0 = *(const float4*)g,       a1 = *(const float4*)(g + 4);
          float4 a2 = *(const float4*)(g + 8), a3 = *(const float4*)(g + 12);
          bf16x8 r0, r1;
          r0[0] = (short)f2bf(a0.x); r0[1] = (short)f2bf(a0.y);
          r0[2] = (short)f2bf(a0.z); r0[3] = (short)f2bf(a0.w);
          r0[4] = (short)f2bf(a1.x); r0[5] = (short)f2bf(a1.y);
          r0[6] = (short)f2bf(a1.z); r0[7] = (short)f2bf(a1.w);
          r1[0] = (short)f2bf(a2.x); r1[1] = (short)f2bf(a2.y);
          r1[2] = (short)f2bf(a2.z); r1[3] = (short)f2bf(a2.w);
          r1[4] = (short)f2bf(a3.x); r1[5] = (short)f2bf(a3.y);
          r1[6] = (short)f2bf(a3.z); r1[7] = (short)f2bf(a3.w);
          int c = c4 << 1;
          *(bf16x8*)&sm.Ab[0][(row << 8) + (((c    ) ^ (row & 7)) << 3)] = r0;
          *(bf16x8*)&sm.Ab[0][(row << 8) + (((c + 1) ^ (row & 7)) << 3)] = r1;
        }
        stage_ld(h0rd, 0);                 // h chunk0 loads in flight
        LDW(0, 0);                         // W chunk0 -> bank0
        bf16x8 X[2][2];
        if (kway < 2) {
          u32 ox0 = bX[0], ox1 = bX[1];
          asm volatile("" : "+v"(ox0), "+v"(ox1));
          X[0][0] = *(const bf16x8*)(X0p + ox0);
          X[0][1] = *(const bf16x8*)(X0p + ox0 + 512u);
          X[1][0] = *(const bf16x8*)(X0p + ox1);
          X[1][1] = *(const bf16x8*)(X0p + ox1 + 512u);
        }
        __syncthreads();                   // x tile (buf0) published
        if (kway < 2) {                    // x-tick on buf0
          const int kin = kway << 5;
#pragma unroll
          for (int mf = 0; mf < 4; ++mf) {
            bf16x8 a = readA(0, mf, kin);
#pragma unroll
            for (int s_ = 0; s_ < 2; ++s_)
#pragma unroll
              for (int f_ = 0; f_ < 2; ++f_)
                acc[mf][s_][f_] = MFMA(a, X[s_][f_], acc[mf][s_][f_], 0, 0, 0);
          }
        }
        stage_st(1);                       // buf1 <- h chunk0 (vmcnt drain)
        __syncthreads();                   // publish buf1
        // chunks c=0..3: data buf alternates 1,0,1,0; W bank = c&1
        stage_ld(h0rd, 256); LDW(1, 1); CHUNK(1, 0); stage_st(0); __syncthreads();
        stage_ld(h0rd, 512); LDW(0, 2); CHUNK(0, 1); stage_st(1); __syncthreads();
        stage_ld(h0rd, 768); LDW(1, 3); CHUNK(1, 0); stage_st(0); __syncthreads();
        CHUNK(0, 1);
        __syncthreads();                   // Ab dead -> G overlay safe
        reduce2();
        ew(h0wr, false);
      }
      gridbar(t);
    } else {
      if (t >= 1) {
        const u16* h0rd = h0b + ((t + 1) & 1) * HB;   // h0(t-1)
        const u16* h1rd = h1b + (t & 1) * HB;         // h1(t-2)
        u16* h1wr = h1b + ((t + 1) & 1) * HB;         // h1(t-1)
        acc_init();
        stage_ld(h0rd, 0); LDW(0, 0);
        stage_st(0); __syncthreads();      // publish buf0 (chunk0)
        // chunks c=0..7: buf = c&1 inverted start (c0 on buf0), bank = c&1
        stage_ld(h0rd, 256); LDW(1, 1); CHUNK(0, 0); stage_st(1); __syncthreads();
        stage_ld(h0rd, 512); LDW(0, 2); CHUNK(1, 1); stage_st(0); __syncthreads();
        stage_ld(h0rd, 768); LDW(1, 3); CHUNK(0, 0); stage_st(1); __syncthreads();
        stage_ld(h1rd, 0);   LDW(0, 4); CHUNK(1, 1); stage_st(0); __syncthreads();
        stage_ld(h1rd, 256); LDW(1, 5); CHUNK(0, 0); stage_st(1); __syncthreads();
        stage_ld(h1rd, 512); LDW(0, 6); CHUNK(1, 1); stage_st(0); __syncthreads();
        stage_ld(h1rd, 768); LDW(1, 7); CHUNK(0, 0); stage_st(1); __syncthreads();
        CHUNK(1, 1);
        __syncthreads();                   // Ab dead -> G overlay safe
        reduce2();
        ew(h1wr, t == 512);
      }
      gridbar(t);
    }
  }

  // ---------------- fc epilogue (verbatim R7) ----------------
  if (blk < 64) {
    const int row = (blk << 2) | w;
    const float* hrow = h1f + ((size_t)row << 10);
#pragma unroll 1
    for (int o = 0; o < 12; ++o) {
      const float* wrow = fcW + o * 1024;
      float p = 0.f;
#pragma unroll
      for (int j = 0; j < 16; ++j) {
        int k = (j << 6) | lane;
        p += __builtin_nontemporal_load(hrow + k) * wrow[k];
      }
#pragma unroll
      for (int off = 32; off > 0; off >>= 1) p += __shfl_down(p, off, 64);
      if (lane == 0) out[row * 12 + o] = p + fcb[o];
    }
  }
}

extern "C" void kernel_launch(void* const* d_in, const int* in_sizes, int n_in,
                              void* d_out, int out_size, void* d_ws, size_t ws_size,
                              hipStream_t stream) {
  (void)in_sizes; (void)n_in; (void)out_size; (void)ws_size;
  const float* x   = (const float*)d_in[0];
  const float* Wx0 = (const float*)d_in[1];
  const float* Wh0 = (const float*)d_in[2];
  const float* b0  = (const float*)d_in[3];
  const float* Wx1 = (const float*)d_in[4];
  const float* Wh1 = (const float*)d_in[5];
  const float* b1  = (const float*)d_in[6];
  const float* fcW = (const float*)d_in[7];
  const float* fcb = (const float*)d_in[8];

  char* ws = (char*)d_ws;
  u16* W1p   = (u16*)ws;                          // 16 MiB packed Wx1|Wh1
  u16* W0p   = (u16*)(ws + (16u << 20));          //  8 MiB packed Wh0
  u16* X0p   = (u16*)(ws + (24u << 20));          // 512 KiB packed Wx0
  u16* h0b   = (u16*)(ws + (25u << 20));          // 2 x 512 KiB
  u16* h1b   = (u16*)(ws + (26u << 20));          // 2 x 512 KiB
  float* h1f = (float*)(ws + (27u << 20));        // 1 MiB
  u32* bar   = (u32*)(ws + (28u << 20));          // counters

  hipMemsetAsync(ws + (25u << 20) + (1 << 19), 0, 1 << 19, stream);  // h0b[1]
  hipMemsetAsync(ws + (26u << 20) + (1 << 19), 0, 1 << 19, stream);  // h1b[1]
  hipMemsetAsync(bar, 0, 4096, stream);

  wconv<<<6272, 256, 0, stream>>>(Wx0, Wh0, Wx1, Wh1, W1p, W0p, X0p);
  lstm_persist<<<512, 256, 0, stream>>>(x, b0, b1, fcW, fcb,
                                        W1p, W0p, X0p,
                                        h0b, h1b, h1f, bar, (float*)d_out);
}